// Round 8
// baseline (1294.014 us; speedup 1.0000x reference)
//
#include <hip/hip_runtime.h>

#define LAYERS 64
#define EMBD   43
#define NOUT   15
#define NTOK   524288

#define MBLK    256
#define THREADS 256

#define ROWB     128                 // bytes per H row (64 bf16)
#define HSBYTES  (MBLK * ROWB)       // 32768 B = entire LDS -> 4 blocks/CU

// W image (R19): per-layer, per-tile FRAGMENT-ORDER global layout, read
// directly by per-lane global_load_dwordx4 (no LDS staging, no barriers).
//   offset(t, hf, lane, e) = t*2048 + hf*1024 + lane*16 + 2e
//   value = B[k = hf*32 + (lane>>4)*8 + e][col = j(G(t), lane&15)]
// k>=44 and invalid-j entries are ZERO.
// R20: i,o gate rows PRE-SCALED by 0.5 (tanh half-arg for sigma); g rows 1.0.
#define IMGSTRIDE 18432              // 9 tiles * 2048 B

typedef short bf16x8 __attribute__((ext_vector_type(8)));
typedef float f32x4  __attribute__((ext_vector_type(4)));
typedef float f32x2  __attribute__((ext_vector_type(2)));

__device__ __forceinline__ unsigned short f2bf(float f) {
  unsigned int u = __builtin_bit_cast(unsigned int, f);
  u = u + 0x7fffu + ((u >> 16) & 1u);           // RNE (cold paths only)
  return (unsigned short)(u >> 16);
}
__device__ __forceinline__ float bf2f(unsigned short s) {
  unsigned int u = ((unsigned int)s) << 16;
  return __builtin_bit_cast(float, u);
}

// [5/4] Pade of tanh as a ratio pair (NO division):
//   tanh(x) ~ N/D,  N = x*((u+105)u+945), D = (15u+420)u+945, u = x^2
// err <1e-5 for |x|<2, ~1.2e-3 peak at |x|~3.6; ratio>1 beyond |x|~3.7
// (caller clamps with fmed3 where args can reach there).
__device__ __forceinline__ void tanh_nd(f32x2 xv, f32x2& N, f32x2& D) {
  const f32x2 c105 = {105.0f, 105.0f};
  const f32x2 c945 = {945.0f, 945.0f};
  const f32x2 c15  = {15.0f, 15.0f};
  const f32x2 c420 = {420.0f, 420.0f};
  f32x2 u = xv * xv;
  N = __builtin_elementwise_fma(u + c105, u, c945) * xv;
  D = __builtin_elementwise_fma(__builtin_elementwise_fma(u, c15, c420), u, c945);
}

// ---------------------------------------------------------------------------
// Pack w_ih (i,g,o gate rows, fp32 -> bf16) into fragment-order images.
// R20 scales: i,o rows x0.5 (sigma(z) = (1+tanh(z/2))/2 -> MFMA yields z/2
// directly); g rows x1.0. Combined bias rides column k=43 (H[43]=1.0).
// tile t = G*3 + {i,g,o}. Column map: G0 -> j=2c, G1 -> j=2c+1, G2 -> j=32+c
// (valid c<=10). k<43: scaled weight; k==43: scaled combined bias; else 0.
// ---------------------------------------------------------------------------
__global__ void pack_w_kernel(const float* __restrict__ w_ih,
                              const float* __restrict__ b_ih,
                              const float* __restrict__ b_hh,
                              unsigned char* __restrict__ wpack) {
  int idx = blockIdx.x * blockDim.x + threadIdx.x;
  if (idx >= LAYERS * 9 * 64) return;
  int lane = idx & 63;
  int t    = (idx >> 6) % 9;
  int l    = idx / (9 * 64);
  int c = lane & 15, q = lane >> 4;
  int G = t / 3, gidx = t % 3;
  int gsel = (gidx == 0) ? 0 : ((gidx == 1) ? 2 : 3);  // i=0, g=2, o=3 of (i,f,g,o)
  float scale = (gidx == 1) ? 1.0f : 0.5f;
  int j = (G == 0) ? 2 * c : ((G == 1) ? 2 * c + 1 : 32 + c);
  int valid = (j < EMBD);
  const float* src = w_ih + ((size_t)l * 172 + (size_t)gsel * EMBD + j) * EMBD;
  float bias = 0.0f;
  if (valid) {
    int R = gsel * EMBD + j;
    bias = (b_ih[l * 172 + R] + b_hh[l * 172 + R]) * scale;
  }
  unsigned char* img = wpack + (size_t)l * IMGSTRIDE + t * 2048 + lane * 16;
  #pragma unroll
  for (int hf = 0; hf < 2; ++hf) {
    union { unsigned short s16[8]; uint4 u; } pk;
    #pragma unroll
    for (int e = 0; e < 8; ++e) {
      int k = hf * 32 + q * 8 + e;
      unsigned short val = 0;
      if (valid && k < EMBD) val = f2bf(src[k] * scale);
      else if (valid && k == EMBD) val = f2bf(bias);
      pk.s16[e] = val;
    }
    *(uint4*)(img + hf * 1024) = pk.u;
  }
}

// ---------------------------------------------------------------------------
// Fused: embedding gather -> 64 LSTM layers -> out proj + log_softmax (fp32).
// Structure = R19 (barrier-free, wave-private H in LDS, W read per-lane
// direct from L2-resident global image, 4 blocks/CU).
// R20: TRANS-FREE epilogue. Cross-round counter model (R15/R18/R19):
// time ~ VALUBusy*t + MfmaUtil*t (issue serialization); VALU budget fit
// shows v_exp/v_rcp ~16 cyc/wave64 (1/8 rate) => the old 4-trans/element
// chain was 81% of all VALU issue. New math, ONE rcp per element:
//   sigma(z) = (1+tanh(z/2))/2; tanh via [5/4] Pade in N/D form (no div);
//   c = sigma(i)tanh(g) = Pc/(2Qc):  Pc=(Di+Ni)Ng, Qc=Di*Dg
//   tanh(c) homogeneous [3/2]:  Pc(60Qc^2+Pc^2) / (2Qc(60Qc^2+6Pc^2))
//   h = sigma(o)*tanh(c) = (Do+No)Pc(60y+x) / (Do*Qc*(240y+24x)),
//       x=Pc^2, y=Qc^2   -> 31 pk + 2 med3 + 2 rcp + 2 mul per PAIR.
// g-Pade overshoot (ratio>1 for |g|>3.7) clamped by fmed3(Ng,Dg,-Dg);
// worst tanh err ~1.2e-3 (|g|~3.6) -- same order as bf16 weight noise.
// Overflow: worst den ~4e30 << f32 max; rcp stays normal.
// H layout = R15's measured-clean swizzle (212K confl):
//   element k of row n at byte n*128 + ((k>>3) ^ (n&7))*16 + (k&7)*2.
// ---------------------------------------------------------------------------
__global__ void __launch_bounds__(THREADS, 4) lstm_kernel(
    const int* __restrict__ tokens,
    const float* __restrict__ emb,
    const unsigned char* __restrict__ wpack,
    const float* __restrict__ w_out,
    const float* __restrict__ b_out,
    float* __restrict__ out) {
  __shared__ __align__(16) unsigned char Hs[HSBYTES];

  const int tid  = threadIdx.x;
  const int lane = tid & 63;
  const int wave = tid >> 6;
  const int c    = lane & 15;
  const int q    = lane >> 4;
  const int row_base = blockIdx.x * MBLK;

  // ---- embedding gather: one thread per row; k=43 slot = 1.0 (bias lane)
  {
    int r = tid;
    int tok = tokens[row_base + r];
    const float* e = emb + (size_t)tok * EMBD;
    unsigned short v[64];
    #pragma unroll
    for (int k = 0; k < EMBD; ++k) v[k] = f2bf(e[k]);
    v[EMBD] = 0x3F80;  // 1.0 bf16: multiplies the bias column of W
    #pragma unroll
    for (int k = EMBD + 1; k < 64; ++k) v[k] = 0;
    #pragma unroll
    for (int g = 0; g < 8; ++g) {
      union { unsigned short s[8]; uint4 u; } pk;
      #pragma unroll
      for (int e2 = 0; e2 < 8; ++e2) pk.s[e2] = v[g * 8 + e2];
      *(uint4*)(Hs + r * ROWB + ((g ^ (r & 7)) * 16)) = pk.u;
    }
  }

  // ---- layer-invariant LDS byte addresses (hoisted out of the loop)
  // NOTE: slot XOR uses (row & 7); row-within-strip rq is 0..15 so mask it.
  int adrA0, adrA1, adrP[4], adrS[4];
  {
    int ra = wave * 64 + c;                       // A row (st=0)
    adrA0 = ra * ROWB + ((q ^ (c & 7)) * 16);
    adrA1 = ra * ROWB + (((4 + q) ^ (c & 7)) * 16);
    #pragma unroll
    for (int r4 = 0; r4 < 4; ++r4) {
      int rq = q * 4 + r4;                        // row within strip, 0..15
      int rm = rq & 7;                            // (row & 7) for the swizzle
      int rr = wave * 64 + rq;                    // C row (st=0)
      adrP[r4] = rr * ROWB + (((c >> 2) ^ rm) * 16) + (c & 3) * 4;          // j=2c pair
      adrS[r4] = rr * ROWB + (((4 + (c >> 3)) ^ rm) * 16) + (c & 7) * 2;    // j=32+c
    }
  }
  // NO __syncthreads anywhere: H rows are wave-private; W comes from global.

  const unsigned char* wl = wpack + lane * 16;    // per-lane W frag pointer
  const f32x4 zf = {0.0f, 0.0f, 0.0f, 0.0f};

  #pragma unroll 1
  for (int l = 0; l < LAYERS; ++l) {
    // A-frags for this layer (own rows; k=43 carries 1.0 so bias rides the MFMA)
    bf16x8 A0[4], A1[4];
    #pragma unroll
    for (int st = 0; st < 4; ++st) {
      A0[st] = *(const bf16x8*)(Hs + adrA0 + st * 2048);
      A1[st] = *(const bf16x8*)(Hs + adrA1 + st * 2048);
    }

    float hh[16];  // G0's h values, held for paired store in G1

    #pragma unroll
    for (int G = 0; G < 3; ++G) {
      f32x4 acc[3][4];  // [gate i/g/o][strip]
      #pragma unroll
      for (int t2 = 0; t2 < 3; ++t2) {
        bf16x8 B0 = *(const bf16x8*)(wl + (G * 3 + t2) * 2048);        // k 0..31
        #pragma unroll
        for (int st = 0; st < 4; ++st)
          acc[t2][st] = __builtin_amdgcn_mfma_f32_16x16x32_bf16(A0[st], B0, zf, 0, 0, 0);
      }
      #pragma unroll
      for (int t2 = 0; t2 < 3; ++t2) {
        bf16x8 B1 = *(const bf16x8*)(wl + (G * 3 + t2) * 2048 + 1024); // k 32..63
        #pragma unroll
        for (int st = 0; st < 4; ++st)
          acc[t2][st] = __builtin_amdgcn_mfma_f32_16x16x32_bf16(A1[st], B1, acc[t2][st], 0, 0, 0);
      }

      // epilogue: lane owns column j(G,c); rows q*4+r4 per strip.
      // acc[0]=i/2, acc[1]=g, acc[2]=o/2. Trans-free rational chain (R20).
      #pragma unroll
      for (int st = 0; st < 4; ++st) {
        #pragma unroll
        for (int hp = 0; hp < 2; ++hp) {
          const int r0 = hp * 2, r1 = hp * 2 + 1;
          f32x2 av, gv, bv;
          av[0] = acc[0][st][r0]; av[1] = acc[0][st][r1];   // i/2
          gv[0] = acc[1][st][r0]; gv[1] = acc[1][st][r1];   // g
          bv[0] = acc[2][st][r0]; bv[1] = acc[2][st][r1];   // o/2
          f32x2 Ni, Di, Ng, Dg, No, Do;
          tanh_nd(av, Ni, Di);
          tanh_nd(gv, Ng, Dg);
          tanh_nd(bv, No, Do);
          // clamp |tanh(g)| <= 1 (Pade ratio >1 for |g|>3.7)
          Ng[0] = __builtin_amdgcn_fmed3f(Ng[0], Dg[0], -Dg[0]);
          Ng[1] = __builtin_amdgcn_fmed3f(Ng[1], Dg[1], -Dg[1]);
          f32x2 Si = Di + Ni;                    // sigma(i) = Si/(2Di)
          f32x2 So = Do + No;                    // sigma(o) = So/(2Do)
          f32x2 Pc = Si * Ng;                    // c = Pc/(2Qc)
          f32x2 Qc = Di * Dg;
          f32x2 x  = Pc * Pc;
          f32x2 y  = Qc * Qc;
          const f32x2 c60  = {60.0f, 60.0f};
          const f32x2 c24  = {24.0f, 24.0f};
          const f32x2 c240 = {240.0f, 240.0f};
          f32x2 n1  = __builtin_elementwise_fma(y, c60, x);        // 60y+x
          f32x2 d1  = __builtin_elementwise_fma(y, c240, x * c24); // 240y+24x
          f32x2 num = (So * Pc) * n1;
          f32x2 den = (Do * Qc) * d1;
          float h0 = num[0] * __builtin_amdgcn_rcpf(den[0]);  // sigma(o)tanh(c)
          float h1 = num[1] * __builtin_amdgcn_rcpf(den[1]);
          if (G == 0) {
            hh[st * 4 + r0] = h0;
            hh[st * 4 + r1] = h1;
          } else if (G == 1) {
            {
              unsigned int u0 = __builtin_bit_cast(unsigned int, hh[st * 4 + r0]) + 0x8000u;
              unsigned int u1 = __builtin_bit_cast(unsigned int, h0) + 0x8000u;
              unsigned int pk = __builtin_amdgcn_perm(u1, u0, 0x07060302u);
              *(unsigned int*)(Hs + adrP[r0] + st * 2048) = pk;  // j=2c, 2c+1
            }
            {
              unsigned int u0 = __builtin_bit_cast(unsigned int, hh[st * 4 + r1]) + 0x8000u;
              unsigned int u1 = __builtin_bit_cast(unsigned int, h1) + 0x8000u;
              unsigned int pk = __builtin_amdgcn_perm(u1, u0, 0x07060302u);
              *(unsigned int*)(Hs + adrP[r1] + st * 2048) = pk;
            }
          } else if (c <= 10) {                                // j=32+c < 43
            unsigned int u1 = (__builtin_bit_cast(unsigned int, h0) + 0x8000u) >> 16;
            *(unsigned short*)(Hs + adrS[r0] + st * 2048) = (unsigned short)u1;
            unsigned int u2 = (__builtin_bit_cast(unsigned int, h1) + 0x8000u) >> 16;
            *(unsigned short*)(Hs + adrS[r1] + st * 2048) = (unsigned short)u2;
          }
        }
      }
    }
    wl += IMGSTRIDE;   // next layer's image
  }

  // ---- output projection (fp32 weights) + log_softmax, one thread per row
  {
    int r = tid;
    float h[EMBD];
    #pragma unroll
    for (int g = 0; g < 6; ++g) {
      union { uint4 u; unsigned short s[8]; } pk;
      pk.u = *(const uint4*)(Hs + r * ROWB + ((g ^ (r & 7)) * 16));
      #pragma unroll
      for (int e2 = 0; e2 < 8; ++e2) {
        int k = g * 8 + e2;
        if (k < EMBD) h[k] = bf2f(pk.s[e2]);
      }
    }
    float logit[NOUT];
    #pragma unroll
    for (int o = 0; o < NOUT; ++o) {
      float sum = b_out[o];
      #pragma unroll
      for (int k = 0; k < EMBD; ++k) sum += w_out[o * EMBD + k] * h[k];
      logit[o] = sum;
    }
    float m = logit[0];
    #pragma unroll
    for (int o = 1; o < NOUT; ++o) m = fmaxf(m, logit[o]);
    float ss = 0.0f;
    #pragma unroll
    for (int o = 0; o < NOUT; ++o) ss += __expf(logit[o] - m);
    float lse = m + __logf(ss);
    float* dst = out + (size_t)(row_base + r) * NOUT;
    #pragma unroll
    for (int o = 0; o < NOUT; ++o) dst[o] = logit[o] - lse;   // fp32 output
  }
}

extern "C" void kernel_launch(void* const* d_in, const int* in_sizes, int n_in,
                              void* d_out, int out_size, void* d_ws, size_t ws_size,
                              hipStream_t stream) {
  const int* tokens     = (const int*)d_in[0];
  const float* emb      = (const float*)d_in[1];
  const float* w_ih     = (const float*)d_in[2];
  const float* b_ih     = (const float*)d_in[4];
  const float* b_hh     = (const float*)d_in[5];
  const float* w_out    = (const float*)d_in[6];
  const float* b_out    = (const float*)d_in[7];
  float* out            = (float*)d_out;

  // Scratch for 64 packed weight images (1,179,648 B). Prefer d_ws; fall back
  // to the mathematically-unused w_hh buffer (d_in[3], 1,893,376 B) otherwise
  // (harness restores inputs from pristine copies before every launch).
  const size_t need = (size_t)LAYERS * IMGSTRIDE;
  unsigned char* wpack = (ws_size >= need) ? (unsigned char*)d_ws
                                           : (unsigned char*)d_in[3];

  pack_w_kernel<<<(LAYERS * 9 * 64 + 255) / 256, 256, 0, stream>>>(w_ih, b_ih, b_hh, wpack);
  lstm_kernel<<<NTOK / MBLK, THREADS, 0, stream>>>(tokens, emb, wpack, w_out, b_out, out);
}

// Round 9
// 1029.069 us; speedup vs baseline: 1.2575x; 1.2575x over previous
//
#include <hip/hip_runtime.h>

#define LAYERS 64
#define EMBD   43
#define NOUT   15
#define NTOK   524288

#define ROWB     128                 // bytes per H/W row (64 bf16)
#define WROWS    144                 // 9 tiles * 16
#define IMGBYTES (WROWS * ROWB)      // 18432 = 18 x 1KB chunks
#define NCHUNK   18

#define MBLK    256
#define THREADS 256

#define NEG_L2E   -1.44269504f      // -log2(e): folded into i,o rows
#define NEG_2L2E  -2.88539008f      // -2*log2(e): folded into g rows

// R21: second-half MFMA is 16x16x16 (K=48 real data; k48-63 were always zero).
// Guarded: if the builtin is absent we fall back to the R15 16x16x32 path.
#if defined(__has_builtin)
#if __has_builtin(__builtin_amdgcn_mfma_f32_16x16x16bf16_1k)
#define HAVE_MFMA16 1
#define MFMA16(a, b, c) __builtin_amdgcn_mfma_f32_16x16x16bf16_1k(a, b, c, 0, 0, 0)
#elif __has_builtin(__builtin_amdgcn_mfma_f32_16x16x16_bf16)
#define HAVE_MFMA16 1
#define MFMA16(a, b, c) __builtin_amdgcn_mfma_f32_16x16x16_bf16(a, b, c, 0, 0, 0)
#endif
#endif
#ifndef HAVE_MFMA16
#define HAVE_MFMA16 0
#endif

typedef short bf16x8 __attribute__((ext_vector_type(8)));
typedef short bf16x4 __attribute__((ext_vector_type(4)));
typedef float f32x4  __attribute__((ext_vector_type(4)));
typedef float f32x2  __attribute__((ext_vector_type(2)));

__device__ __forceinline__ unsigned short f2bf(float f) {
  unsigned int u = __builtin_bit_cast(unsigned int, f);
  u = u + 0x7fffu + ((u >> 16) & 1u);           // RNE (cold paths only)
  return (unsigned short)(u >> 16);
}
__device__ __forceinline__ float bf2f(unsigned short s) {
  unsigned int u = ((unsigned int)s) << 16;
  return __builtin_bit_cast(float, u);
}

// R21: one-instruction packed f32->bf16 (RNE). Replaces 3-op add/add/perm.
__device__ __forceinline__ unsigned int cvtpk_bf16(float lo, float hi) {
  unsigned int r;
  asm("v_cvt_pk_bf16_f32 %0, %1, %2" : "=v"(r) : "v"(lo), "v"(hi));
  return r;
}

// ---------------------------------------------------------------------------
// Pack w_ih (i,g,o gate rows only, fp32 -> bf16, PRE-SCALED by -log2e or
// -2log2e) into per-layer LDS images. Image row n = tile*16 + c;
// tile = G*3 + {i,g,o}. Column map: G0 -> j=2c, G1 -> j=2c+1, G2 -> j=32+c
// (valid c<=10) -- G0/G1 pairing enables packed b32 h-stores.
// Element k of row n at byte n*128 + ((k>>3) ^ (n&7))*16 + (k&7)*2.
// k<43: scaled weight; k==43: scaled combined bias (H[k=43]==1.0); k>43: 0.
// ---------------------------------------------------------------------------
__global__ void pack_w_kernel(const float* __restrict__ w_ih,
                              const float* __restrict__ b_ih,
                              const float* __restrict__ b_hh,
                              unsigned char* __restrict__ wpack) {
  int idx = blockIdx.x * blockDim.x + threadIdx.x;
  if (idx >= LAYERS * WROWS) return;
  int l = idx / WROWS, n = idx % WROWS;
  int t = n >> 4, c = n & 15;
  int G = t / 3, gidx = t % 3;
  int gsel = (gidx == 0) ? 0 : ((gidx == 1) ? 2 : 3);  // i=0, g=2, o=3 of (i,f,g,o)
  float scale = (gidx == 1) ? NEG_2L2E : NEG_L2E;
  int j = (G == 0) ? 2 * c : ((G == 1) ? 2 * c + 1 : 32 + c);
  int valid = (j < EMBD);
  const float* src = w_ih + ((size_t)l * 172 + (size_t)gsel * EMBD + j) * EMBD;
  float bias = 0.0f;
  if (valid) {
    int R = gsel * EMBD + j;
    bias = (b_ih[l * 172 + R] + b_hh[l * 172 + R]) * scale;
  }
  unsigned char* dst = wpack + (size_t)l * IMGBYTES + n * ROWB;
  #pragma unroll
  for (int g = 0; g < 8; ++g) {
    union { unsigned short s[8]; uint4 v; } pk;
    #pragma unroll
    for (int e = 0; e < 8; ++e) {
      int k = g * 8 + e;
      unsigned short val = 0;
      if (valid && k < EMBD) val = f2bf(src[k] * scale);
      else if (valid && k == EMBD) val = f2bf(bias);
      pk.s[e] = val;
    }
    int slot = g ^ (n & 7);
    *(uint4*)(dst + slot * 16) = pk.v;
  }
}

// ---------------------------------------------------------------------------
// Fused: embedding gather -> 64 LSTM layers -> out proj + log_softmax (fp32).
// Base = R15 (best measured, 1058us): 256 rows/block, 4 waves x 4 strips,
// W staged in LDS (global_load_lds, 2 barriers/layer), packed (v2f32)
// homogeneous-Pade epilogue (3 exp2 + 1 rcp / element):
//   t1=2^acc_i=e^-i, t2=2^acc_g=e^-2g, t3=2^acc_o=e^-o
//   h = sigma(o)*tanh(P/Q) = P(15Q^2+P^2) / ( Q(2.5Q^2+P^2) * 6(1+t3) )
// R21 deltas: (1) second-half MFMA 16x16x16 over k32..47 only (k48-63 were
// structurally zero) -- 25% less MFMA execute, A1/B1 ds_read b128->b64;
// (2) v_cvt_pk_bf16_f32 for all h stores (3 ops -> 1).
// HW-model journal: R20 proved trans ops are issue-cheap (separate pipe,
// cost = chain latency only); trading trans for packed ALU issues LOSES
// (+27%). R18/R19 proved occupancy 3->4 blk/CU and barrier removal are
// neutral: the SIMD issue port is saturated (VALUBusy+MfmaUtil ~ 100%).
// Only issue-count / execute-occupancy reductions pay. 96B LDS strides
// conflict structurally (R16/R17); only pow2 strides + XOR swizzle clean.
// ---------------------------------------------------------------------------
__global__ void __launch_bounds__(THREADS, 3) lstm_kernel(
    const int* __restrict__ tokens,
    const float* __restrict__ emb,
    const unsigned char* __restrict__ wpack,
    const float* __restrict__ w_out,
    const float* __restrict__ b_out,
    float* __restrict__ out) {
  __shared__ __align__(16) unsigned char Hs[MBLK * ROWB];  // 32768 B
  __shared__ __align__(16) unsigned char Ws[IMGBYTES];     // 18432 B

  const int tid  = threadIdx.x;
  const int lane = tid & 63;
  const int wave = tid >> 6;
  const int c    = lane & 15;
  const int q    = lane >> 4;
  const int row_base = blockIdx.x * MBLK;

  // ---- prefetch layer-0 weights into LDS (async, drained at first barrier)
  {
    const unsigned char* src = wpack;
    #pragma unroll
    for (int ch = 0; ch < 5; ++ch) {
      int chunk = wave + ch * 4;
      if (chunk < NCHUNK)
        __builtin_amdgcn_global_load_lds(
            (const __attribute__((address_space(1))) void*)(src + chunk * 1024 + lane * 16),
            (__attribute__((address_space(3))) void*)(Ws + chunk * 1024),
            16, 0, 0);
    }
  }

  // ---- embedding gather: one thread per row; k=43 slot = 1.0 (bias lane)
  {
    int r = tid;
    int tok = tokens[row_base + r];
    const float* e = emb + (size_t)tok * EMBD;
    unsigned short v[64];
    #pragma unroll
    for (int k = 0; k < EMBD; ++k) v[k] = f2bf(e[k]);
    v[EMBD] = 0x3F80;  // 1.0 bf16: multiplies the bias column of W
    #pragma unroll
    for (int k = EMBD + 1; k < 64; ++k) v[k] = 0;
    #pragma unroll
    for (int g = 0; g < 8; ++g) {
      union { unsigned short s[8]; uint4 u; } pk;
      #pragma unroll
      for (int e2 = 0; e2 < 8; ++e2) pk.s[e2] = v[g * 8 + e2];
      *(uint4*)(Hs + r * ROWB + ((g ^ (r & 7)) * 16)) = pk.u;
    }
  }

  // ---- layer-invariant LDS byte addresses (hoisted out of the loop)
  // NOTE: slot XOR uses (row & 7); row-within-strip rq is 0..15 so mask it.
  // A1/B1 (k=32+4q, 8B): byte = ((4+(q>>1)) ^ (row&7))*16 + (q&1)*8.
  // Bank check: rows (c, c+8) share the slot -> 2-way (free floor).
  int adrA0, adrA1, adrB0, adrB1, adrP[4], adrS[4];
  {
    int ra = wave * 64 + c;                       // A row (st=0)
    adrA0 = ra * ROWB + ((q ^ (c & 7)) * 16);
    adrB0 = c * ROWB + ((q ^ (c & 7)) * 16);      // B row n = t*16+c; t via imm
#if HAVE_MFMA16
    adrA1 = ra * ROWB + (((4 + (q >> 1)) ^ (c & 7)) * 16) + (q & 1) * 8;
    adrB1 = c * ROWB + (((4 + (q >> 1)) ^ (c & 7)) * 16) + (q & 1) * 8;
#else
    adrA1 = ra * ROWB + (((4 + q) ^ (c & 7)) * 16);
    adrB1 = c * ROWB + (((4 + q) ^ (c & 7)) * 16);
#endif
    #pragma unroll
    for (int r4 = 0; r4 < 4; ++r4) {
      int rq = q * 4 + r4;                        // row within strip, 0..15
      int rm = rq & 7;                            // (row & 7) for the swizzle
      int rr = wave * 64 + rq;                    // C row (st=0)
      adrP[r4] = rr * ROWB + (((c >> 2) ^ rm) * 16) + (c & 3) * 4;          // j=2c pair
      adrS[r4] = rr * ROWB + (((4 + (c >> 3)) ^ rm) * 16) + (c & 7) * 2;    // j=32+c
    }
  }
  __syncthreads();  // W[0] resident, H tile ready

  const f32x4 zf = {0.0f, 0.0f, 0.0f, 0.0f};

  #pragma unroll 1
  for (int l = 0; l < LAYERS; ++l) {
    // A-frags for this layer (own rows; k=43 carries 1.0 so bias rides the MFMA)
    bf16x8 A0[4];
#if HAVE_MFMA16
    bf16x4 A1[4];
#else
    bf16x8 A1[4];
#endif
    #pragma unroll
    for (int st = 0; st < 4; ++st) {
      A0[st] = *(const bf16x8*)(Hs + adrA0 + st * 2048);
#if HAVE_MFMA16
      A1[st] = *(const bf16x4*)(Hs + adrA1 + st * 2048);
#else
      A1[st] = *(const bf16x8*)(Hs + adrA1 + st * 2048);
#endif
    }

    float hh[16];  // G0's h values, held for paired store in G1

    #pragma unroll
    for (int G = 0; G < 3; ++G) {
      f32x4 acc[3][4];  // [gate i/g/o][strip]
      #pragma unroll
      for (int t2 = 0; t2 < 3; ++t2) {
        int off = (G * 3 + t2) * 2048;
        bf16x8 B0 = *(const bf16x8*)(Ws + adrB0 + off);
        #pragma unroll
        for (int st = 0; st < 4; ++st)
          acc[t2][st] = __builtin_amdgcn_mfma_f32_16x16x32_bf16(A0[st], B0, zf, 0, 0, 0);
      }
      #pragma unroll
      for (int t2 = 0; t2 < 3; ++t2) {
        int off = (G * 3 + t2) * 2048;
#if HAVE_MFMA16
        bf16x4 B1 = *(const bf16x4*)(Ws + adrB1 + off);
        #pragma unroll
        for (int st = 0; st < 4; ++st)
          acc[t2][st] = MFMA16(A1[st], B1, acc[t2][st]);
#else
        bf16x8 B1 = *(const bf16x8*)(Ws + adrB1 + off);
        #pragma unroll
        for (int st = 0; st < 4; ++st)
          acc[t2][st] = __builtin_amdgcn_mfma_f32_16x16x32_bf16(A1[st], B1, acc[t2][st], 0, 0, 0);
#endif
      }

      if (G == 2) {
        __syncthreads();  // all waves done reading Ws for layer l
        if (l + 1 < LAYERS) {
          const unsigned char* src = wpack + (size_t)(l + 1) * IMGBYTES;
          #pragma unroll
          for (int ch = 0; ch < 5; ++ch) {
            int chunk = wave + ch * 4;
            if (chunk < NCHUNK)
              __builtin_amdgcn_global_load_lds(
                  (const __attribute__((address_space(1))) void*)(src + chunk * 1024 + lane * 16),
                  (__attribute__((address_space(3))) void*)(Ws + chunk * 1024),
                  16, 0, 0);
          }
        }
      }

      // epilogue: lane owns column j(G,c); rows q*4+r4 per strip.
      // Packed (v2f32) homogeneous-Pade over r4 pairs: 6 exp2 + 2 rcp +
      // 11 packed VALU per 2 elements. Stores via v_cvt_pk_bf16_f32 (R21).
      #pragma unroll
      for (int st = 0; st < 4; ++st) {
        #pragma unroll
        for (int hp = 0; hp < 2; ++hp) {
          const int r0 = hp * 2, r1 = hp * 2 + 1;
          f32x2 t1, t2v, t3;
          t1[0]  = __builtin_amdgcn_exp2f(acc[0][st][r0]);   // e^-i
          t1[1]  = __builtin_amdgcn_exp2f(acc[0][st][r1]);
          t2v[0] = __builtin_amdgcn_exp2f(acc[1][st][r0]);   // e^-2g
          t2v[1] = __builtin_amdgcn_exp2f(acc[1][st][r1]);
          t3[0]  = __builtin_amdgcn_exp2f(acc[2][st][r0]);   // e^-o
          t3[1]  = __builtin_amdgcn_exp2f(acc[2][st][r1]);
          const f32x2 one = {1.0f, 1.0f};
          const f32x2 two = {2.0f, 2.0f};
          const f32x2 k15 = {15.0f, 15.0f};
          const f32x2 k25 = {2.5f, 2.5f};
          const f32x2 k6  = {6.0f, 6.0f};
          f32x2 u   = t2v + one;
          f32x2 Qd  = __builtin_elementwise_fma(t1, u, u);    // Q=(1+t1)(1+t2)
          f32x2 P   = two - u;                                // 1 - t2
          f32x2 x   = P * P;
          f32x2 y   = Qd * Qd;
          f32x2 n1  = __builtin_elementwise_fma(y, k15, x);   // 15Q^2 + P^2
          f32x2 dt  = __builtin_elementwise_fma(y, k25, x);   // (15Q^2+6P^2)/6
          f32x2 nP  = P * n1;
          f32x2 dQ  = Qd * dt;
          f32x2 v6  = __builtin_elementwise_fma(t3, k6, k6);  // 6(1+t3)
          f32x2 den = dQ * v6;
          float h0 = nP[0] * __builtin_amdgcn_rcpf(den[0]);   // sigma(o)*tanh(c)
          float h1 = nP[1] * __builtin_amdgcn_rcpf(den[1]);
          if (G == 0) {
            hh[st * 4 + r0] = h0;
            hh[st * 4 + r1] = h1;
          } else if (G == 1) {
            *(unsigned int*)(Hs + adrP[r0] + st * 2048) =
                cvtpk_bf16(hh[st * 4 + r0], h0);               // j=2c, 2c+1
            *(unsigned int*)(Hs + adrP[r1] + st * 2048) =
                cvtpk_bf16(hh[st * 4 + r1], h1);
          } else if (c <= 10) {                                // j=32+c < 43
            unsigned int pr = cvtpk_bf16(h0, h1);
            *(unsigned short*)(Hs + adrS[r0] + st * 2048) = (unsigned short)pr;
            *(unsigned short*)(Hs + adrS[r1] + st * 2048) = (unsigned short)(pr >> 16);
          }
        }
      }
    }
    __syncthreads();  // W[l+1] resident (vmcnt drained); Ws stable for next layer
  }

  // ---- output projection (fp32 weights) + log_softmax, one thread per row
  {
    int r = tid;
    float h[EMBD];
    #pragma unroll
    for (int g = 0; g < 6; ++g) {
      union { uint4 u; unsigned short s[8]; } pk;
      pk.u = *(const uint4*)(Hs + r * ROWB + ((g ^ (r & 7)) * 16));
      #pragma unroll
      for (int e2 = 0; e2 < 8; ++e2) {
        int k = g * 8 + e2;
        if (k < EMBD) h[k] = bf2f(pk.s[e2]);
      }
    }
    float logit[NOUT];
    #pragma unroll
    for (int o = 0; o < NOUT; ++o) {
      float sum = b_out[o];
      #pragma unroll
      for (int k = 0; k < EMBD; ++k) sum += w_out[o * EMBD + k] * h[k];
      logit[o] = sum;
    }
    float m = logit[0];
    #pragma unroll
    for (int o = 1; o < NOUT; ++o) m = fmaxf(m, logit[o]);
    float ss = 0.0f;
    #pragma unroll
    for (int o = 0; o < NOUT; ++o) ss += __expf(logit[o] - m);
    float lse = m + __logf(ss);
    float* dst = out + (size_t)(row_base + r) * NOUT;
    #pragma unroll
    for (int o = 0; o < NOUT; ++o) dst[o] = logit[o] - lse;   // fp32 output
  }
}

extern "C" void kernel_launch(void* const* d_in, const int* in_sizes, int n_in,
                              void* d_out, int out_size, void* d_ws, size_t ws_size,
                              hipStream_t stream) {
  const int* tokens     = (const int*)d_in[0];
  const float* emb      = (const float*)d_in[1];
  const float* w_ih     = (const float*)d_in[2];
  const float* b_ih     = (const float*)d_in[4];
  const float* b_hh     = (const float*)d_in[5];
  const float* w_out    = (const float*)d_in[6];
  const float* b_out    = (const float*)d_in[7];
  float* out            = (float*)d_out;

  // Scratch for 64 packed weight images (1,179,648 B). Prefer d_ws; fall back
  // to the mathematically-unused w_hh buffer (d_in[3], 1,893,376 B) otherwise
  // (harness restores inputs from pristine copies before every launch).
  const size_t need = (size_t)LAYERS * IMGBYTES;
  unsigned char* wpack = (ws_size >= need) ? (unsigned char*)d_ws
                                           : (unsigned char*)d_in[3];

  pack_w_kernel<<<(LAYERS * WROWS + 255) / 256, 256, 0, stream>>>(w_ih, b_ih, b_hh, wpack);
  lstm_kernel<<<NTOK / MBLK, THREADS, 0, stream>>>(tokens, emb, wpack, w_out, b_out, out);
}